// Round 5
// baseline (403.630 us; speedup 1.0000x reference)
//
#include <hip/hip_runtime.h>
#include <hip/hip_bf16.h>
#include <stdint.h>

#define N_TOK 8192
#define DIM   1024
#define HID   2048
#define NEXP  8
#define RB    256   // route blocks (32 tokens each)

typedef __bf16 bf16x8 __attribute__((ext_vector_type(8)));
typedef float  f32x4  __attribute__((ext_vector_type(4)));
typedef unsigned short u16x8 __attribute__((ext_vector_type(8)));
typedef unsigned short u16x4 __attribute__((ext_vector_type(4)));

__device__ __forceinline__ float bits2f(unsigned short u) {
    union { unsigned int i; float f; } c; c.i = ((unsigned int)u) << 16; return c.f;
}
__device__ __forceinline__ unsigned short f2bfbits(float f) {
    __hip_bfloat16 h = __float2bfloat16(f);
    return *(unsigned short*)&h;
}

// ---- async global->LDS, 16B per lane ----
__device__ __forceinline__ void load_lds16(const void* g, void* l) {
    __builtin_amdgcn_global_load_lds(
        (const __attribute__((address_space(1))) void*)g,
        (__attribute__((address_space(3))) void*)l,
        16, 0, 0);
}

#define VMW(Nv) asm volatile("s_waitcnt vmcnt(" #Nv ")" ::: "memory")
#define BARv()  asm volatile("s_barrier" ::: "memory")
#define LGKM0() do { asm volatile("s_waitcnt lgkmcnt(0)" ::: "memory"); \
                     __builtin_amdgcn_sched_barrier(0); } while (0)

// ======================= phase 1: route + weight transpose/convert (fused) ==========
__global__ __launch_bounds__(256) void fused_pre_k(
    const float* __restrict__ x,
    const float* __restrict__ gate,
    const float* __restrict__ w1,
    const float* __restrict__ w2,
    int* __restrict__ epack, float* __restrict__ pw,
    unsigned short* __restrict__ xb,
    int* __restrict__ H0, int* __restrict__ H1, float* __restrict__ Pblk,
    unsigned short* __restrict__ w1t, unsigned short* __restrict__ w2t)
{
    __shared__ __align__(16) union {
        struct { float gw[NEXP][16][64]; int h0[NEXP]; int h1[NEXP]; float p[NEXP]; } r;
        unsigned short tile[64][72];
    } S;
    const int tid = threadIdx.x;
    const int bx  = blockIdx.x;

    if (bx < RB) {
        if (tid < NEXP) { S.r.h0[tid] = 0; S.r.h1[tid] = 0; S.r.p[tid] = 0.f; }
        for (int idx = tid; idx < NEXP * DIM; idx += 256) {
            int e = idx >> 10, rem = idx & 1023, i = rem >> 6, l = rem & 63;
            S.r.gw[e][i][l] = gate[e * DIM + l * 16 + i];
        }
        __syncthreads();
        int w = tid >> 6, lane = tid & 63;
        float prAcc[NEXP];
        #pragma unroll
        for (int e = 0; e < NEXP; ++e) prAcc[e] = 0.f;
        for (int it = 0; it < 8; ++it) {
            int token = bx * 32 + w * 8 + it;
            const float* xr = x + (size_t)token * DIM + lane * 16;
            float xv[16];
            #pragma unroll
            for (int q = 0; q < 4; ++q) {
                float4 v = *(const float4*)(xr + q * 4);
                xv[q * 4 + 0] = v.x; xv[q * 4 + 1] = v.y; xv[q * 4 + 2] = v.z; xv[q * 4 + 3] = v.w;
            }
            {
                u16x8 o0, o1;
                #pragma unroll
                for (int i = 0; i < 8; ++i) { o0[i] = f2bfbits(xv[i]); o1[i] = f2bfbits(xv[8 + i]); }
                unsigned short* dst = xb + (size_t)token * DIM + lane * 16;
                *(u16x8*)dst = o0;
                *(u16x8*)(dst + 8) = o1;
            }
            float lg[NEXP];
            #pragma unroll
            for (int e = 0; e < NEXP; ++e) {
                float s = 0.f;
                #pragma unroll
                for (int i = 0; i < 16; ++i) s += xv[i] * S.r.gw[e][i][lane];
                lg[e] = s;
            }
            #pragma unroll
            for (int off = 32; off > 0; off >>= 1)
                #pragma unroll
                for (int e = 0; e < NEXP; ++e) lg[e] += __shfl_xor(lg[e], off);
            float mx = lg[0]; int am = 0;
            #pragma unroll
            for (int e = 1; e < NEXP; ++e) if (lg[e] > mx) { mx = lg[e]; am = e; }
            float pr[NEXP], se = 0.f;
            #pragma unroll
            for (int e = 0; e < NEXP; ++e) { pr[e] = __expf(lg[e] - mx); se += pr[e]; }
            float inv = 1.f / se;
            #pragma unroll
            for (int e = 0; e < NEXP; ++e) pr[e] *= inv;
            float m2 = -1.f; int a2 = 0;
            #pragma unroll
            for (int e = 0; e < NEXP; ++e) if (e != am && pr[e] > m2) { m2 = pr[e]; a2 = e; }
            float psum = pr[am] + m2;
            if (lane == 0) {
                epack[token] = am | (a2 << 4);
                pw[token * 2] = pr[am] / psum;
                pw[token * 2 + 1] = m2 / psum;
                atomicAdd(&S.r.h0[am], 1);
                atomicAdd(&S.r.h1[a2], 1);
                #pragma unroll
                for (int e = 0; e < NEXP; ++e) prAcc[e] += pr[e];
            }
        }
        if (lane == 0) {
            #pragma unroll
            for (int e = 0; e < NEXP; ++e) atomicAdd(&S.r.p[e], prAcc[e]);
        }
        __syncthreads();
        if (tid < NEXP) {
            H0[bx * NEXP + tid] = S.r.h0[tid];
            H1[bx * NEXP + tid] = S.r.h1[tid];
            Pblk[bx * NEXP + tid] = S.r.p[tid];
        }
        return;
    }

    int bT = bx - RB;
    const float* inp; unsigned short* outp;
    int R, C, r0, c0;
    if (bT < 4096) {
        int e = bT >> 9, rem = bT & 511;
        R = DIM; C = HID;
        inp = w1 + (size_t)e * R * C; outp = w1t + (size_t)e * R * C;
        r0 = (rem >> 5) << 6; c0 = (rem & 31) << 6;
    } else {
        int b2 = bT - 4096;
        int e = b2 >> 9, rem = b2 & 511;
        R = HID; C = DIM;
        inp = w2 + (size_t)e * R * C; outp = w2t + (size_t)e * R * C;
        r0 = (rem >> 4) << 6; c0 = (rem & 15) << 6;
    }
    {
        int r = tid >> 2, cseg = (tid & 3) * 16;
        const float* src = inp + (size_t)(r0 + r) * C + c0 + cseg;
        #pragma unroll
        for (int q = 0; q < 4; ++q) {
            float4 v = *(const float4*)(src + q * 4);
            S.tile[r][cseg + q * 4 + 0] = f2bfbits(v.x);
            S.tile[r][cseg + q * 4 + 1] = f2bfbits(v.y);
            S.tile[r][cseg + q * 4 + 2] = f2bfbits(v.z);
            S.tile[r][cseg + q * 4 + 3] = f2bfbits(v.w);
        }
    }
    __syncthreads();
    {
        // read remap: consecutive lanes read consecutive columns of one row ->
        // 2 lanes per 4B word, conflict-free (old map: rows 16 apart -> 4-way bank 0)
        int c = tid & 63, rseg = (tid >> 6) * 16;
        unsigned short* dst = outp + (size_t)(c0 + c) * R + r0 + rseg;
        #pragma unroll
        for (int h = 0; h < 2; ++h) {
            u16x8 o;
            #pragma unroll
            for (int i = 0; i < 8; ++i) o[i] = S.tile[rseg + h * 8 + i][c];
            *(u16x8*)(dst + h * 8) = o;
        }
    }
}

// ======================= phase 2: scan (1 block) =======================
__global__ __launch_bounds__(256) void scan_k(
    const int* __restrict__ H0, const int* __restrict__ H1,
    const float* __restrict__ Pblk,
    int* __restrict__ bbL, int* __restrict__ counts, int* __restrict__ basep,
    float* __restrict__ aux)
{
    __shared__ int h0S[RB * NEXP], h1S[RB * NEXP], bbS[RB * NEXP];
    __shared__ float pSh[RB * NEXP];
    __shared__ int cS[NEXP], fS[NEXP];
    __shared__ float psS[NEXP];
    int tid = threadIdx.x;
    for (int i = tid; i < RB * NEXP; i += 256) { h0S[i] = H0[i]; h1S[i] = H1[i]; pSh[i] = Pblk[i]; }
    __syncthreads();
    if (tid < NEXP) {
        int run = 0, f = 0; float p = 0.f;
        for (int b = 0; b < RB; ++b) {
            int i = b * NEXP + tid;
            bbS[i] = run;
            run += h0S[i] + h1S[i];
            f += h0S[i];
            p += pSh[i];
        }
        cS[tid] = run; fS[tid] = f; psS[tid] = p;
        counts[tid] = run;
    }
    __syncthreads();
    if (tid == 0) {
        int b = 0; float s = 0.f;
        for (int e = 0; e < NEXP; ++e) {
            basep[e] = b; b += cS[e];
            s += (fS[e] * (1.f / 8192.f)) * (psS[e] * (1.f / 8192.f));
        }
        aux[0] = 0.01f * 8.f * s;
    }
    __syncthreads();
    for (int i = tid; i < RB * NEXP; i += 256) bbL[i] = bbS[i];
}

// ======================= phase 3: scatter (ballot ranking, no atomics) ==============
__global__ __launch_bounds__(256) void scatter_k(
    const int* __restrict__ epack, const int* __restrict__ bbL,
    int* __restrict__ tok_list, int* __restrict__ code)
{
    int tid = threadIdx.x;
    int w = tid >> 6, lane = tid & 63;
    int g = blockIdx.x * 4 + w;
    int token = g * 32 + (lane >> 1);
    int ep = epack[token];
    int e = (lane & 1) ? ((ep >> 4) & 0xF) : (ep & 0xF);
    unsigned long long lower = (lane == 0) ? 0ull : ((~0ull) >> (64 - lane));
    unsigned long long mymask = 0;
    #pragma unroll
    for (int ee = 0; ee < NEXP; ++ee) {
        unsigned long long m = __ballot(e == ee);
        if (ee == e) mymask = m;
    }
    int rank = __popcll(mymask & lower);
    int slot = bbL[g * NEXP + e] + rank;
    tok_list[e * N_TOK + slot] = token;
    code[token * 2 + (lane & 1)] = (e << 13) | slot;
}

// ======================= 256x256 8-wave grouped GEMM, deep-lead 4-phase =============
// Geometry/maps identical to the round-4 passing kernel (linear A/B slot maps,
// XOR chunk swizzle, per-wave C rows mh*128+wr*64+ii*16+ml, cols nh*128+wc*32+
// jj*16+ml). Only the pipeline changed: stage issues move to the barrier that
// frees their region, giving 6-7 phase lead (~1.5 tiles, m201-depth) on double
// buffer. Per tile t (bo=b(t), nx=b(t+1); note b(t+2)=bo):
//   p0: VMW(10); bar; issue G3(t+1)->nx   [nx A1 last read p2(t-1), freed here]
//       read A0,B0; lgkm0; mm(0,0)
//   p1: VMW(10); bar; issue G0G1(t+2)->bo [bo A0/B0 last read p0(t), freed here]
//       read B1;    lgkm0; mm(0,1)
//   p2: VMW(12); bar; issue G2(t+2)->bo   [bo B1 last read p1(t), freed here;
//       read A1;    lgkm0; mm(1,0)         disjoint from this phase's A1 read]
//   p3: mm(1,1)
// Ledger (instr-granular, in-order): before each wait outstanding = 14/12/14;
// VMW(10/10/12) retires exactly {G0G1(t)}/{G2(t)}/{G3(t)}. Leads 7/7/6 phases.
// Prologue = exact stream order G0G1(0),G2(0),G3(0),G0G1(1),G2(1) (14 instrs).
// Tail: clamp t+1,t+2 to KT-1 -> schedule stays uniform; each clamped write
// targets a region with no remaining readers (audited); VMW(0) after the loop.
template<bool GATHER, bool RELU, int KT, int NTL>
__global__ __launch_bounds__(512, 2) void moe_gemm256(
    const unsigned short* __restrict__ A,
    const unsigned short* __restrict__ B,
    unsigned short* __restrict__ O,
    const int* __restrict__ counts,
    const int* __restrict__ basep,
    const int* __restrict__ tok_list,
    const int N)
{
    constexpr int K = KT * 64;
    const int bid = blockIdx.x;
    const int e  = bid & 7;            // expert == XCD (blocks round-robin XCDs)
    const int q  = bid >> 3;
    const int m0 = (q >> NTL) * 256;
    const int n0 = (q & ((1 << NTL) - 1)) * 256;
    const int cnt = counts[e];
    if (m0 >= cnt) return;
    const int bas = basep[e];

    const int tid = threadIdx.x;
    const int wid = tid >> 6, lane = tid & 63;
    const int wr = wid >> 2, wc = wid & 3;
    const int q4 = lane >> 4, ml = lane & 15;

    __shared__ __align__(16) unsigned short lds[65536];   // 128 KB

    // ---- staging source pointers (pre-swizzled global chunk) ----
    const int u  = tid >> 3;                     // slot within 64-slot instr
    const int gk = (tid & 7) ^ (u & 7);          // global k-chunk for LDS pos tid&7
    const unsigned short* aR[4];
    #pragma unroll
    for (int g = 0; g < 4; ++g) {
        int slot = m0 + g * 64 + u;
        int row;
        if (GATHER) row = (slot < cnt) ? tok_list[e * N_TOK + slot] : 0;
        else        row = bas + ((slot < cnt) ? slot : (cnt - 1));
        aR[g] = A + (size_t)row * K + gk * 8;
    }
    const unsigned short* Be = B + (size_t)e * (size_t)N * K;
    const unsigned short* bR = Be + (size_t)(n0 + u) * K + gk * 8;
    const int std_ = tid * 8;                    // per-thread LDS dest (ushorts)

    auto gA01 = [&](int bo_, int t_) {           // G0: A rows [0,128)
        load_lds16(aR[0] + t_ * 64, &lds[bo_ + std_]);
        load_lds16(aR[1] + t_ * 64, &lds[bo_ + 4096 + std_]);
    };
    auto gB01 = [&](int bo_, int t_) {           // G1: B cols [0,128)
        load_lds16(bR + t_ * 64,                    &lds[bo_ + 16384 + std_]);
        load_lds16(bR + (size_t)64 * K + t_ * 64,   &lds[bo_ + 20480 + std_]);
    };
    auto gB23 = [&](int bo_, int t_) {           // G2: B cols [128,256)
        load_lds16(bR + (size_t)128 * K + t_ * 64,  &lds[bo_ + 24576 + std_]);
        load_lds16(bR + (size_t)192 * K + t_ * 64,  &lds[bo_ + 28672 + std_]);
    };
    auto gA23 = [&](int bo_, int t_) {           // G3: A rows [128,256)
        load_lds16(aR[2] + t_ * 64, &lds[bo_ + 8192 + std_]);
        load_lds16(aR[3] + t_ * 64, &lds[bo_ + 12288 + std_]);
    };

    f32x4 acc[8][4];
    #pragma unroll
    for (int i = 0; i < 8; ++i)
        #pragma unroll
        for (int j = 0; j < 4; ++j) acc[i][j] = f32x4{0.f, 0.f, 0.f, 0.f};

    const int cswz = ml & 7;
    const int cp0 = (q4 ^ cswz) * 8;             // kh=0 read position
    const int cp1 = ((4 + q4) ^ cswz) * 8;       // kh=1 read position
    const int aoff = (wr * 64 + ml) * 64;        // + mh*8192 + ii*1024
    const int boff = 16384 + (wc * 32 + ml) * 64;// + nh*8192 + jj*1024

    bf16x8 aF[4][2], bF[4][2];
    auto readA = [&](int bo_, int mh) {
        #pragma unroll
        for (int ii = 0; ii < 4; ++ii) {
            int o = bo_ + aoff + mh * 8192 + ii * 1024;
            aF[ii][0] = *(const bf16x8*)&lds[o + cp0];
            aF[ii][1] = *(const bf16x8*)&lds[o + cp1];
        }
    };
    auto readB = [&](int bo_, int nh) {
        #pragma unroll
        for (int jj = 0; jj < 2; ++jj) {
            int o = bo_ + boff + nh * 8192 + jj * 1024;
            bF[nh * 2 + jj][0] = *(const bf16x8*)&lds[o + cp0];
            bF[nh * 2 + jj][1] = *(const bf16x8*)&lds[o + cp1];
        }
    };
    auto mm = [&](int mh, int nh) {
        __builtin_amdgcn_s_setprio(1);
        #pragma unroll
        for (int ii = 0; ii < 4; ++ii)
            #pragma unroll
            for (int jj = 0; jj < 2; ++jj) {
                acc[mh * 4 + ii][nh * 2 + jj] = __builtin_amdgcn_mfma_f32_16x16x32_bf16(
                    aF[ii][0], bF[nh * 2 + jj][0], acc[mh * 4 + ii][nh * 2 + jj], 0, 0, 0);
                acc[mh * 4 + ii][nh * 2 + jj] = __builtin_amdgcn_mfma_f32_16x16x32_bf16(
                    aF[ii][1], bF[nh * 2 + jj][1], acc[mh * 4 + ii][nh * 2 + jj], 0, 0, 0);
            }
        __builtin_amdgcn_s_setprio(0);
    };

    // prologue (exact stream order): G0G1(0), G2(0), G3(0), G0G1(1), G2(1)
    gA01(0, 0); gB01(0, 0);
    gB23(0, 0);
    gA23(0, 0);
    gA01(32768, 1); gB01(32768, 1);
    gB23(32768, 1);

    for (int t = 0; t < KT; ++t) {
        const int bo = (t & 1) << 15;
        const int nx = bo ^ 32768;
        const int t1 = (t + 1 < KT) ? t + 1 : KT - 1;
        const int t2 = (t + 2 < KT) ? t + 2 : KT - 1;
        // p0
        VMW(10); BARv();
        gA23(nx, t1);                      // G3(t+1)
        readA(bo, 0); readB(bo, 0);
        LGKM0();
        mm(0, 0);
        // p1
        VMW(10); BARv();
        gA01(bo, t2); gB01(bo, t2);        // G0G1(t+2)
        readB(bo, 1);
        LGKM0();
        mm(0, 1);
        // p2
        VMW(12); BARv();
        gB23(bo, t2);                      // G2(t+2)
        readA(bo, 1);
        LGKM0();
        mm(1, 0);
        // p3 (registers only)
        mm(1, 1);
    }
    VMW(0);   // drain clamped tail loads before LDS goes away

    #pragma unroll
    for (int mh = 0; mh < 2; ++mh)
        #pragma unroll
        for (int ii = 0; ii < 4; ++ii) {
            int rbase = mh * 128 + wr * 64 + ii * 16 + q4 * 4;
            #pragma unroll
            for (int r = 0; r < 4; ++r) {
                int slot = m0 + rbase + r;
                if (slot < cnt) {
                    unsigned short* orow = O + (size_t)(bas + slot) * N + n0 + wc * 32 + ml;
                    #pragma unroll
                    for (int nh = 0; nh < 2; ++nh)
                        #pragma unroll
                        for (int jj = 0; jj < 2; ++jj) {
                            float v = acc[mh * 4 + ii][nh * 2 + jj][r];
                            if (RELU) v = v > 0.f ? v : 0.f;
                            orow[nh * 128 + jj * 16] = f2bfbits(v);
                        }
                }
            }
        }
}

// ======================= combine: out[t] = p0*Y[r0] + p1*Y[r1] ===========
__global__ __launch_bounds__(256) void combine_k(
    const unsigned short* __restrict__ Y,
    const int* __restrict__ code, const float* __restrict__ pw,
    const int* __restrict__ basep,
    float* __restrict__ out)
{
    int t = blockIdx.x;
    int c0 = code[t * 2], c1 = code[t * 2 + 1];
    float p0 = pw[t * 2], p1 = pw[t * 2 + 1];
    size_t r0 = (size_t)(basep[c0 >> 13] + (c0 & 0x1FFF)) * DIM;
    size_t r1 = (size_t)(basep[c1 >> 13] + (c1 & 0x1FFF)) * DIM;
    int d = threadIdx.x * 4;
    u16x4 a = *(const u16x4*)(Y + r0 + d);
    u16x4 b = *(const u16x4*)(Y + r1 + d);
    float4 o;
    o.x = p0 * bits2f(a[0]) + p1 * bits2f(b[0]);
    o.y = p0 * bits2f(a[1]) + p1 * bits2f(b[1]);
    o.z = p0 * bits2f(a[2]) + p1 * bits2f(b[2]);
    o.w = p0 * bits2f(a[3]) + p1 * bits2f(b[3]);
    *(float4*)(out + (size_t)t * DIM + d) = o;
}

// ======================= launch =======================
extern "C" void kernel_launch(void* const* d_in, const int* in_sizes, int n_in,
                              void* d_out, int out_size, void* d_ws, size_t ws_size,
                              hipStream_t stream)
{
    const float* x    = (const float*)d_in[0];
    const float* gate = (const float*)d_in[1];
    const float* w1   = (const float*)d_in[2];
    const float* w2   = (const float*)d_in[3];
    float* out = (float*)d_out;

    char* ws = (char*)d_ws;
    int*   counts   = (int*)(ws + 0);
    int*   basep    = (int*)(ws + 256);
    int*   epack    = (int*)(ws + 1024);                      // 32 KB
    int*   H0       = (int*)(ws + 1024 + 32768);
    int*   H1       = (int*)(ws + 1024 + 40960);
    float* Pblk     = (float*)(ws + 1024 + 49152);
    int*   bbL      = (int*)(ws + 1024 + 57344);
    int*   tok_list = (int*)(ws + 131072);                    // 256 KB
    int*   code     = (int*)(ws + 131072 + 262144);           // 64 KB
    float* pw       = (float*)(ws + 131072 + 262144 + 65536); // 64 KB
    // big buffers (all bf16):
    //   [1MB, 33MB)   w1t
    //   [33MB, 65MB)  w2t
    //   [65MB,129MB)  hidden
    //   [129MB,161MB) xb (first 16MB; dead after GEMM1) -> reused as Y
    unsigned short* w1t    = (unsigned short*)(ws + (1 << 20));
    unsigned short* w2t    = (unsigned short*)(ws + (1 << 20) + 33554432);
    unsigned short* hidden = (unsigned short*)(ws + (1 << 20) + 67108864);
    unsigned short* xb     = (unsigned short*)(ws + (1 << 20) + 134217728);
    unsigned short* Y      = xb;   // GEMM2 output (xb dead by then)

    fused_pre_k<<<RB + 8192, 256, 0, stream>>>(x, gate, w1, w2, epack, pw, xb,
                                               H0, H1, Pblk, w1t, w2t);
    scan_k<<<1, 256, 0, stream>>>(H0, H1, Pblk, bbL, counts, basep, out + (size_t)N_TOK * DIM);
    scatter_k<<<64, 256, 0, stream>>>(epack, bbL, tok_list, code);
    // flat 1-D grids: expert = bid&7 pins each expert to one XCD (B-panel L2-resident)
    moe_gemm256<true, true, DIM / 64, 3><<<NEXP * 32 * 8, 512, 0, stream>>>(
        xb, w1t, hidden, counts, basep, tok_list, HID);
    moe_gemm256<false, false, HID / 64, 2><<<NEXP * 32 * 4, 512, 0, stream>>>(
        hidden, w2t, Y, counts, basep, tok_list, DIM);
    combine_k<<<N_TOK, 256, 0, stream>>>(Y, code, pw, basep, out);
}